// Round 3
// baseline (485.995 us; speedup 1.0000x reference)
//
#include <hip/hip_runtime.h>
#include <hip/hip_bf16.h>
#include <stdint.h>

// MoE SwiGLU, sparse top-2 routing, bf16 MFMA GEMMs, fp32 accumulate.
// N=2048 tokens, D=1024, I=2048, E=8, top_k=2 (hard-coded).

#define N_TOK 2048
#define DIM   1024
#define IDIM  2048
#define NEXP  8

typedef short s16x8 __attribute__((ext_vector_type(8)));   // 8 bf16 bit-patterns (4 VGPRs)
typedef float f32x4 __attribute__((ext_vector_type(4)));

// Static device scratch (independent of ws_size). ~137 MB total.
__device__ __align__(256) __hip_bfloat16 g_xb [(size_t)N_TOK*DIM];        // x in bf16
__device__ __align__(256) __hip_bfloat16 g_wgT[(size_t)NEXP*IDIM*DIM];    // w_gate^T  [e][i][d]
__device__ __align__(256) __hip_bfloat16 g_wuT[(size_t)NEXP*IDIM*DIM];    // w_up^T    [e][i][d]
__device__ __align__(256) __hip_bfloat16 g_wdT[(size_t)NEXP*DIM*IDIM];    // w_down^T  [e][d][i]
__device__ __align__(256) __hip_bfloat16 g_h  [(size_t)N_TOK*2*IDIM];     // silu(g)*u, compact rows
__device__ __align__(256) float          g_y  [(size_t)N_TOK*2*DIM];      // h @ Wd, compact rows
__device__ int   g_topi[N_TOK*2];
__device__ float g_topp[N_TOK*2];
__device__ int   g_rows[N_TOK*2];    // per-expert compact token lists
__device__ int   g_slot[N_TOK*2];    // token -> its 2 compact slots
__device__ float g_probs[N_TOK*2];   // per-slot combine prob
__device__ int   g_meta[32];         // [0:8) counts, [8:16) cursors, [16:25) offs

__device__ __forceinline__ void load_lds16(const void* g, void* l){
  // 16B-per-lane direct global->LDS (dest = wave-uniform base + lane*16)
  __builtin_amdgcn_global_load_lds(
      (const __attribute__((address_space(1))) unsigned int*)g,
      (__attribute__((address_space(3))) unsigned int*)l, 16, 0, 0);
}

// ---------------- prep: x -> bf16, zero meta ----------------
__global__ void k_cast_x(const float* __restrict__ x){
  if (blockIdx.x == 0 && threadIdx.x < 32) g_meta[threadIdx.x] = 0;
  int i = blockIdx.x*256 + threadIdx.x;          // 524288 float4s total
  float4 v = ((const float4*)x)[i];
  union { ushort4 u; __hip_bfloat16 b[4]; } o;
  o.b[0] = __float2bfloat16(v.x); o.b[1] = __float2bfloat16(v.y);
  o.b[2] = __float2bfloat16(v.z); o.b[3] = __float2bfloat16(v.w);
  ((ushort4*)g_xb)[i] = o.u;
}

// ---------------- prep: transpose + cast the 3 weight tensors ----------------
// src [R][C] fp32 -> dst [C][R] bf16, 64x64 tiles through padded LDS.
__global__ void k_transpose(const float* __restrict__ wg, const float* __restrict__ wu,
                            const float* __restrict__ wd){
  __shared__ float tile[64][65];
  const int which = blockIdx.z;
  const int e     = blockIdx.y;
  const int R = (which == 2) ? IDIM : DIM;
  const int C = (which == 2) ? DIM  : IDIM;
  const float* src = ((which == 0) ? wg : (which == 1) ? wu : wd) + (size_t)e*DIM*IDIM;
  __hip_bfloat16* dst = ((which == 0) ? g_wgT : (which == 1) ? g_wuT : g_wdT) + (size_t)e*DIM*IDIM;
  const int ntr = R >> 6;
  const int tr = blockIdx.x % ntr, tc = blockIdx.x / ntr;
  const int r0 = tr*64, c0 = tc*64;
  const int t = threadIdx.x;
  #pragma unroll
  for (int it = 0; it < 4; ++it){
    int s = t + it*256; int ri = s >> 4, c4 = (s & 15)*4;
    float4 v = *(const float4*)(src + (size_t)(r0+ri)*C + c0 + c4);
    tile[ri][c4+0] = v.x; tile[ri][c4+1] = v.y; tile[ri][c4+2] = v.z; tile[ri][c4+3] = v.w;
  }
  __syncthreads();
  #pragma unroll
  for (int it = 0; it < 4; ++it){
    int s = t + it*256; int ci = s >> 4, r4 = (s & 15)*4;
    union { ushort4 u; __hip_bfloat16 b[4]; } o;
    #pragma unroll
    for (int j = 0; j < 4; ++j) o.b[j] = __float2bfloat16(tile[r4+j][ci]);
    *(ushort4*)((unsigned short*)dst + (size_t)(c0+ci)*R + r0 + r4) = o.u;
  }
}

// ---------------- router: logits, top-2, softmax, counts ----------------
__global__ void k_router(const float* __restrict__ x, const float* __restrict__ wr){
  const int w = threadIdx.x >> 6, lane = threadIdx.x & 63;
  const int n = blockIdx.x*4 + w;                // one wave per token
  float acc[8] = {0,0,0,0,0,0,0,0};
  const float* xrow = x + (size_t)n*DIM;
  #pragma unroll
  for (int i = 0; i < 16; ++i){
    int d = lane + i*64;
    float xv = xrow[d];
    const float4* wp = (const float4*)(wr + (size_t)d*8);
    float4 w0 = wp[0], w1 = wp[1];
    acc[0] += xv*w0.x; acc[1] += xv*w0.y; acc[2] += xv*w0.z; acc[3] += xv*w0.w;
    acc[4] += xv*w1.x; acc[5] += xv*w1.y; acc[6] += xv*w1.z; acc[7] += xv*w1.w;
  }
  #pragma unroll
  for (int e = 0; e < 8; ++e)
    #pragma unroll
    for (int off = 32; off; off >>= 1) acc[e] += __shfl_xor(acc[e], off);
  if (lane == 0){
    int i0 = -1, i1 = -1; float m0 = -1e30f, m1 = -1e30f;
    #pragma unroll
    for (int e = 0; e < 8; ++e){
      float v = acc[e];
      if (v > m0){ m1 = m0; i1 = i0; m0 = v; i0 = e; }
      else if (v > m1){ m1 = v; i1 = e; }
    }
    float ex = expf(m1 - m0);
    float p0 = 1.f/(1.f+ex), p1 = ex/(1.f+ex);
    g_topi[n*2]   = i0; g_topi[n*2+1] = i1;
    g_topp[n*2]   = p0; g_topp[n*2+1] = p1;
    atomicAdd(&g_meta[i0], 1); atomicAdd(&g_meta[i1], 1);
  }
}

// ---------------- scan + scatter (fused, one block) ----------------
__global__ void k_scan_scatter(){
  if (threadIdx.x == 0){
    int a = 0;
    for (int e = 0; e < 8; ++e){ g_meta[16+e] = a; a += g_meta[e]; }
    g_meta[24] = a;
  }
  __syncthreads();
  for (int it = 0; it < N_TOK/256; ++it){
    const int n = it*256 + threadIdx.x;
    #pragma unroll
    for (int s = 0; s < 2; ++s){
      int e = g_topi[n*2+s]; float p = g_topp[n*2+s];
      int pos = atomicAdd(&g_meta[8+e], 1);
      int slot = g_meta[16+e] + pos;
      g_rows [slot] = n;
      g_probs[slot] = p;
      g_slot [n*2+s] = slot;
    }
  }
}

// ---------------- stage A: h = silu(x@Wg) * (x@Wu), per expert ----------------
// 128x128 tile, BK=32, 4 waves, dual accumulators, XOR-swizzled LDS.
__global__ __launch_bounds__(256, 2) void k_mlp1(){
  const int e = blockIdx.z;
  // XCD-aware swizzle of the 256-block (tm,ti) plane: same-XCD blocks share B-panels.
  const int flat  = blockIdx.x + 16*blockIdx.y;
  const int flat2 = (flat & 7)*32 + (flat >> 3);
  const int tm = flat2 & 15, ti = flat2 >> 4;
  const int cnt = g_meta[e];
  if (tm*128 >= cnt) return;
  const int off = g_meta[16+e];
  __shared__ __align__(16) __hip_bfloat16 lA [2][128*32];
  __shared__ __align__(16) __hip_bfloat16 lBg[2][128*32];
  __shared__ __align__(16) __hip_bfloat16 lBu[2][128*32];
  const int t = threadIdx.x, w = t >> 6, lane = t & 63;
  // --- staging addresses (2 rows per thread per tile, 16B per lane) ---
  const int rr = lane >> 2;
  const int r0 = w*32 + rr, r1 = r0 + 16;
  // LDS slot kg' holds data kg = kg' ^ S(r), S(r) = (r&3)^((r>>2)&3)  (<=2-way banks)
  const int swb = (((lane & 3) ^ (rr & 3) ^ ((rr >> 2) & 3)) << 4);
  const int tok0 = g_rows[off + min(tm*128 + r0, cnt-1)];
  const int tok1 = g_rows[off + min(tm*128 + r1, cnt-1)];
  const char* sA0 = (const char*)(g_xb + (size_t)tok0*DIM) + swb;
  const char* sA1 = (const char*)(g_xb + (size_t)tok1*DIM) + swb;
  const size_t wB = ((size_t)e*IDIM + (size_t)ti*128)*DIM;
  const char* sG0 = (const char*)(g_wgT + wB + (size_t)r0*DIM) + swb;
  const char* sG1 = (const char*)(g_wgT + wB + (size_t)r1*DIM) + swb;
  const char* sU0 = (const char*)(g_wuT + wB + (size_t)r0*DIM) + swb;
  const char* sU1 = (const char*)(g_wuT + wB + (size_t)r1*DIM) + swb;
  const int d0 = (w*2+0)*1024, d1 = (w*2+1)*1024;
  auto stage = [&](int b, int ks){
    const int kb = ks*64;
    load_lds16(sA0+kb, (char*)lA [b] + d0);
    load_lds16(sA1+kb, (char*)lA [b] + d1);
    load_lds16(sG0+kb, (char*)lBg[b] + d0);
    load_lds16(sG1+kb, (char*)lBg[b] + d1);
    load_lds16(sU0+kb, (char*)lBu[b] + d0);
    load_lds16(sU1+kb, (char*)lBu[b] + d1);
  };
  f32x4 accg[4][4] = {}, accu[4][4] = {};
  const int wr = w >> 1, wc = w & 1;
  const int swr = (((lane >> 4) ^ (lane & 3) ^ ((lane >> 2) & 3)) << 4);
  const int aOff = (wr*64 + (lane & 15))*64 + swr;
  const int bOff = (wc*64 + (lane & 15))*64 + swr;
  stage(0, 0);
  __syncthreads();
  for (int ks = 0; ks < DIM/32; ++ks){
    const int cur = ks & 1;
    if (ks + 1 < DIM/32) stage(cur ^ 1, ks + 1);
    s16x8 af[4], bg[4], bu[4];
    #pragma unroll
    for (int f = 0; f < 4; ++f){
      af[f] = *(const s16x8*)((const char*)lA [cur] + aOff + f*1024);
      bg[f] = *(const s16x8*)((const char*)lBg[cur] + bOff + f*1024);
      bu[f] = *(const s16x8*)((const char*)lBu[cur] + bOff + f*1024);
    }
    #pragma unroll
    for (int m = 0; m < 4; ++m)
      #pragma unroll
      for (int n = 0; n < 4; ++n){
        accg[m][n] = __builtin_amdgcn_mfma_f32_16x16x32_bf16(af[m], bg[n], accg[m][n], 0, 0, 0);
        accu[m][n] = __builtin_amdgcn_mfma_f32_16x16x32_bf16(af[m], bu[n], accu[m][n], 0, 0, 0);
      }
    __syncthreads();
  }
  const int rbase = wr*64 + ((lane >> 4) << 2);
  const int cbase = ti*128 + wc*64 + (lane & 15);
  #pragma unroll
  for (int m = 0; m < 4; ++m){
    #pragma unroll
    for (int j = 0; j < 4; ++j){
      const int lr = rbase + m*16 + j;
      const int gi = tm*128 + lr;
      if (gi < cnt){
        __hip_bfloat16* hp = g_h + (size_t)(off + gi)*IDIM + cbase;
        #pragma unroll
        for (int n = 0; n < 4; ++n){
          float gv = accg[m][n][j], uv = accu[m][n][j];
          float hv = gv / (1.f + __expf(-gv)) * uv;   // silu(g)*u
          hp[n*16] = __float2bfloat16(hv);
        }
      }
    }
  }
}

// ---------------- stage B: y = h @ Wd (compact rows, unscaled) ----------------
__global__ __launch_bounds__(256, 2) void k_mlp2(){
  const int e = blockIdx.z;
  const int flat  = blockIdx.x + 16*blockIdx.y;   // 128 blocks/expert
  const int flat2 = (flat & 7)*16 + (flat >> 3);
  const int tm = flat2 & 15, bd = flat2 >> 4;
  const int cnt = g_meta[e];
  if (tm*128 >= cnt) return;
  const int off = g_meta[16+e];
  __shared__ __align__(16) __hip_bfloat16 lA[2][128*32];
  __shared__ __align__(16) __hip_bfloat16 lB[2][128*32];
  const int t = threadIdx.x, w = t >> 6, lane = t & 63;
  const int rr = lane >> 2;
  const int r0 = w*32 + rr, r1 = r0 + 16;
  const int swb = (((lane & 3) ^ (rr & 3) ^ ((rr >> 2) & 3)) << 4);
  const int h0 = off + min(tm*128 + r0, cnt-1);
  const int h1 = off + min(tm*128 + r1, cnt-1);
  const char* sA0 = (const char*)(g_h + (size_t)h0*IDIM) + swb;
  const char* sA1 = (const char*)(g_h + (size_t)h1*IDIM) + swb;
  const size_t wB = ((size_t)e*DIM + (size_t)bd*128)*IDIM;
  const char* sB0 = (const char*)(g_wdT + wB + (size_t)r0*IDIM) + swb;
  const char* sB1 = (const char*)(g_wdT + wB + (size_t)r1*IDIM) + swb;
  const int d0 = (w*2+0)*1024, d1 = (w*2+1)*1024;
  auto stage = [&](int b, int ks){
    const int kb = ks*64;
    load_lds16(sA0+kb, (char*)lA[b] + d0);
    load_lds16(sA1+kb, (char*)lA[b] + d1);
    load_lds16(sB0+kb, (char*)lB[b] + d0);
    load_lds16(sB1+kb, (char*)lB[b] + d1);
  };
  f32x4 acc[4][4] = {};
  const int wr = w >> 1, wc = w & 1;
  const int swr = (((lane >> 4) ^ (lane & 3) ^ ((lane >> 2) & 3)) << 4);
  const int aOff = (wr*64 + (lane & 15))*64 + swr;
  const int bOff = (wc*64 + (lane & 15))*64 + swr;
  stage(0, 0);
  __syncthreads();
  for (int ks = 0; ks < IDIM/32; ++ks){
    const int cur = ks & 1;
    if (ks + 1 < IDIM/32) stage(cur ^ 1, ks + 1);
    s16x8 af[4], bw[4];
    #pragma unroll
    for (int f = 0; f < 4; ++f){
      af[f] = *(const s16x8*)((const char*)lA[cur] + aOff + f*1024);
      bw[f] = *(const s16x8*)((const char*)lB[cur] + bOff + f*1024);
    }
    #pragma unroll
    for (int m = 0; m < 4; ++m)
      #pragma unroll
      for (int n = 0; n < 4; ++n)
        acc[m][n] = __builtin_amdgcn_mfma_f32_16x16x32_bf16(af[m], bw[n], acc[m][n], 0, 0, 0);
    __syncthreads();
  }
  const int rbase = wr*64 + ((lane >> 4) << 2);
  const int cb = bd*128 + wc*64 + (lane & 15);
  #pragma unroll
  for (int m = 0; m < 4; ++m){
    #pragma unroll
    for (int j = 0; j < 4; ++j){
      const int lr = rbase + m*16 + j;
      const int gi = tm*128 + lr;
      if (gi < cnt){
        float* yp = g_y + (size_t)(off + gi)*DIM + cb;
        #pragma unroll
        for (int n = 0; n < 4; ++n)
          yp[n*16] = acc[m][n][j];
      }
    }
  }
}

// ---------------- combine: out[n] = p0*y[slot0] + p1*y[slot1] ----------------
__global__ void k_combine(float* __restrict__ out){
  const int n = blockIdx.x, t = threadIdx.x;     // 256 threads, one float4 each
  const int s0 = g_slot[n*2], s1 = g_slot[n*2+1];
  const float p0 = g_probs[s0], p1 = g_probs[s1];
  float4 a = ((const float4*)(g_y + (size_t)s0*DIM))[t];
  float4 b = ((const float4*)(g_y + (size_t)s1*DIM))[t];
  float4 o;
  o.x = p0*a.x + p1*b.x; o.y = p0*a.y + p1*b.y;
  o.z = p0*a.z + p1*b.z; o.w = p0*a.w + p1*b.w;
  ((float4*)(out + (size_t)n*DIM))[t] = o;
}

extern "C" void kernel_launch(void* const* d_in, const int* in_sizes, int n_in,
                              void* d_out, int out_size, void* d_ws, size_t ws_size,
                              hipStream_t stream){
  (void)in_sizes; (void)n_in; (void)d_ws; (void)ws_size; (void)out_size;
  const float* x  = (const float*)d_in[0];
  const float* wr = (const float*)d_in[1];
  const float* wg = (const float*)d_in[2];
  const float* wu = (const float*)d_in[3];
  const float* wd = (const float*)d_in[4];
  float* out = (float*)d_out;

  k_cast_x      <<<2048, 256, 0, stream>>>(x);
  k_router      <<<N_TOK/4, 256, 0, stream>>>(x, wr);
  k_scan_scatter<<<1, 256, 0, stream>>>();
  k_transpose   <<<dim3(512, NEXP, 3), 256, 0, stream>>>(wg, wu, wd);
  k_mlp1        <<<dim3(16, IDIM/128, NEXP), 256, 0, stream>>>();
  k_mlp2        <<<dim3(16, DIM/128, NEXP), 256, 0, stream>>>();
  k_combine     <<<N_TOK, 256, 0, stream>>>(out);
}

// Round 9
// 414.347 us; speedup vs baseline: 1.1729x; 1.1729x over previous
//
#include <hip/hip_runtime.h>
#include <hip/hip_bf16.h>
#include <stdint.h>

// MoE SwiGLU, sparse top-2 routing, bf16 MFMA GEMMs, fp32 accumulate.
// N=2048 tokens, D=1024, I=2048, E=8, top_k=2 (hard-coded).
// Round 9: resubmit of the 128x64 retile (rounds 4-8 never benched:
// acquisition timeouts). Round-3 profile of the 128x128 version showed
// latency-bound (MfmaUtil 16%, Occ 12%, HBM 10%) -> 2x block parallelism.

#define N_TOK 2048
#define DIM   1024
#define IDIM  2048
#define NEXP  8

typedef short s16x8 __attribute__((ext_vector_type(8)));   // 8 bf16 bit-patterns (4 VGPRs)
typedef float f32x4 __attribute__((ext_vector_type(4)));

// Static device scratch. ~153 MB total.
__device__ __align__(256) __hip_bfloat16 g_xb [(size_t)N_TOK*DIM];        // x in bf16
__device__ __align__(256) __hip_bfloat16 g_wgT[(size_t)NEXP*IDIM*DIM];    // w_gate^T  [e][i][d]
__device__ __align__(256) __hip_bfloat16 g_wuT[(size_t)NEXP*IDIM*DIM];    // w_up^T    [e][i][d]
__device__ __align__(256) __hip_bfloat16 g_wdT[(size_t)NEXP*DIM*IDIM];    // w_down^T  [e][d][i]
__device__ __align__(256) __hip_bfloat16 g_h  [(size_t)N_TOK*2*IDIM];     // silu(g)*u, compact rows
__device__ __align__(256) float          g_y  [(size_t)2*N_TOK*2*DIM];    // h @ Wd partials (2 K-halves)
__device__ int   g_topi[N_TOK*2];
__device__ float g_topp[N_TOK*2];
__device__ int   g_rows[N_TOK*2];    // per-expert compact token lists
__device__ int   g_slot[N_TOK*2];    // token -> its 2 compact slots
__device__ float g_probs[N_TOK*2];   // per-slot combine prob
__device__ int   g_meta[32];         // [0:8) counts, [8:16) cursors, [16:25) offs

__device__ __forceinline__ void load_lds16(const void* g, void* l){
  // 16B-per-lane direct global->LDS (dest = wave-uniform base + lane*16)
  __builtin_amdgcn_global_load_lds(
      (const __attribute__((address_space(1))) unsigned int*)g,
      (__attribute__((address_space(3))) unsigned int*)l, 16, 0, 0);
}

// ---------------- prep: x -> bf16, zero meta ----------------
__global__ void k_cast_x(const float* __restrict__ x){
  if (blockIdx.x == 0 && threadIdx.x < 32) g_meta[threadIdx.x] = 0;
  int i = blockIdx.x*256 + threadIdx.x;          // 524288 float4s total
  float4 v = ((const float4*)x)[i];
  union { ushort4 u; __hip_bfloat16 b[4]; } o;
  o.b[0] = __float2bfloat16(v.x); o.b[1] = __float2bfloat16(v.y);
  o.b[2] = __float2bfloat16(v.z); o.b[3] = __float2bfloat16(v.w);
  ((ushort4*)g_xb)[i] = o.u;
}

// ---------------- prep: transpose + cast the 3 weight tensors ----------------
__global__ void k_transpose(const float* __restrict__ wg, const float* __restrict__ wu,
                            const float* __restrict__ wd){
  __shared__ float tile[64][65];
  const int which = blockIdx.z;
  const int e     = blockIdx.y;
  const int R = (which == 2) ? IDIM : DIM;
  const int C = (which == 2) ? DIM  : IDIM;
  const float* src = ((which == 0) ? wg : (which == 1) ? wu : wd) + (size_t)e*DIM*IDIM;
  __hip_bfloat16* dst = ((which == 0) ? g_wgT : (which == 1) ? g_wuT : g_wdT) + (size_t)e*DIM*IDIM;
  const int ntr = R >> 6;
  const int tr = blockIdx.x % ntr, tc = blockIdx.x / ntr;
  const int r0 = tr*64, c0 = tc*64;
  const int t = threadIdx.x;
  #pragma unroll
  for (int it = 0; it < 4; ++it){
    int s = t + it*256; int ri = s >> 4, c4 = (s & 15)*4;
    float4 v = *(const float4*)(src + (size_t)(r0+ri)*C + c0 + c4);
    tile[ri][c4+0] = v.x; tile[ri][c4+1] = v.y; tile[ri][c4+2] = v.z; tile[ri][c4+3] = v.w;
  }
  __syncthreads();
  #pragma unroll
  for (int it = 0; it < 4; ++it){
    int s = t + it*256; int ci = s >> 4, r4 = (s & 15)*4;
    union { ushort4 u; __hip_bfloat16 b[4]; } o;
    #pragma unroll
    for (int j = 0; j < 4; ++j) o.b[j] = __float2bfloat16(tile[r4+j][ci]);
    *(ushort4*)((unsigned short*)dst + (size_t)(c0+ci)*R + r0 + r4) = o.u;
  }
}

// ---------------- router: logits, top-2, softmax, counts ----------------
__global__ void k_router(const float* __restrict__ x, const float* __restrict__ wr){
  const int w = threadIdx.x >> 6, lane = threadIdx.x & 63;
  const int n = blockIdx.x*4 + w;                // one wave per token
  float acc[8] = {0,0,0,0,0,0,0,0};
  const float* xrow = x + (size_t)n*DIM;
  #pragma unroll
  for (int i = 0; i < 16; ++i){
    int d = lane + i*64;
    float xv = xrow[d];
    const float4* wp = (const float4*)(wr + (size_t)d*8);
    float4 w0 = wp[0], w1 = wp[1];
    acc[0] += xv*w0.x; acc[1] += xv*w0.y; acc[2] += xv*w0.z; acc[3] += xv*w0.w;
    acc[4] += xv*w1.x; acc[5] += xv*w1.y; acc[6] += xv*w1.z; acc[7] += xv*w1.w;
  }
  #pragma unroll
  for (int e = 0; e < 8; ++e)
    #pragma unroll
    for (int off = 32; off; off >>= 1) acc[e] += __shfl_xor(acc[e], off);
  if (lane == 0){
    int i0 = -1, i1 = -1; float m0 = -1e30f, m1 = -1e30f;
    #pragma unroll
    for (int e = 0; e < 8; ++e){
      float v = acc[e];
      if (v > m0){ m1 = m0; i1 = i0; m0 = v; i0 = e; }
      else if (v > m1){ m1 = v; i1 = e; }
    }
    float ex = expf(m1 - m0);
    float p0 = 1.f/(1.f+ex), p1 = ex/(1.f+ex);
    g_topi[n*2]   = i0; g_topi[n*2+1] = i1;
    g_topp[n*2]   = p0; g_topp[n*2+1] = p1;
    atomicAdd(&g_meta[i0], 1); atomicAdd(&g_meta[i1], 1);
  }
}

// ---------------- scan + scatter (fused, one block) ----------------
__global__ void k_scan_scatter(){
  if (threadIdx.x == 0){
    int a = 0;
    for (int e = 0; e < 8; ++e){ g_meta[16+e] = a; a += g_meta[e]; }
    g_meta[24] = a;
  }
  __syncthreads();
  for (int it = 0; it < N_TOK/256; ++it){
    const int n = it*256 + threadIdx.x;
    #pragma unroll
    for (int s = 0; s < 2; ++s){
      int e = g_topi[n*2+s]; float p = g_topp[n*2+s];
      int pos = atomicAdd(&g_meta[8+e], 1);
      int slot = g_meta[16+e] + pos;
      g_rows [slot] = n;
      g_probs[slot] = p;
      g_slot [n*2+s] = slot;
    }
  }
}

// ---------------- stage A: h = silu(x@Wg) * (x@Wu), per expert ----------------
// 128M x 64N tile, BK=32, 4 waves (each 64x32, acc 4x2x2). LDS 32KB.
__global__ __launch_bounds__(256, 4) void k_mlp1(){
  const int e = blockIdx.z;
  // XCD swizzle of the 512-block (tm,ti) plane (512 % 8 == 0 -> bijective)
  const int flat  = blockIdx.x + 16*blockIdx.y;
  const int flat2 = (flat & 7)*64 + (flat >> 3);
  const int tm = flat2 & 15, ti = flat2 >> 4;    // ti in [0,32)
  const int cnt = g_meta[e];
  if (tm*128 >= cnt) return;
  const int off = g_meta[16+e];
  __shared__ __align__(16) __hip_bfloat16 lA [2][128*32];   // 16KB
  __shared__ __align__(16) __hip_bfloat16 lBg[2][64*32];    // 8KB
  __shared__ __align__(16) __hip_bfloat16 lBu[2][64*32];    // 8KB
  const int t = threadIdx.x, w = t >> 6, lane = t & 63;
  // --- staging: thread t owns row r=t>>2 (A also r+64), k-quarter kq=t&3 ---
  const int r  = t >> 2, kq = t & 3;
  const int swb = ((kq ^ (r & 3) ^ ((r >> 2) & 3)) << 4);   // S(r) invariant under r+=64
  const int tok0 = g_rows[off + min(tm*128 + r,      cnt-1)];
  const int tok1 = g_rows[off + min(tm*128 + r + 64, cnt-1)];
  const char* sA0 = (const char*)(g_xb + (size_t)tok0*DIM) + swb;
  const char* sA1 = (const char*)(g_xb + (size_t)tok1*DIM) + swb;
  const size_t wB = ((size_t)e*IDIM + (size_t)ti*64)*DIM;
  const char* sG0 = (const char*)(g_wgT + wB + (size_t)r*DIM) + swb;
  const char* sU0 = (const char*)(g_wuT + wB + (size_t)r*DIM) + swb;
  const int dA = w*1024;                         // wave-uniform LDS bases
  auto stage = [&](int b, int ks){
    const int kb = ks*64;
    load_lds16(sA0+kb, (char*)lA [b] + dA);
    load_lds16(sA1+kb, (char*)lA [b] + dA + 4096);
    load_lds16(sG0+kb, (char*)lBg[b] + dA);
    load_lds16(sU0+kb, (char*)lBu[b] + dA);
  };
  f32x4 accg[4][2] = {}, accu[4][2] = {};
  const int wr = w >> 1, wc = w & 1;
  const int l15 = lane & 15;
  const int swr = (((lane >> 4) ^ (lane & 3) ^ ((lane >> 2) & 3)) << 4);
  const int aOff = (wr*64 + l15)*64 + swr;
  const int bOff = (wc*32 + l15)*64 + swr;
  stage(0, 0);
  __syncthreads();
  for (int ks = 0; ks < DIM/32; ++ks){
    const int cur = ks & 1;
    if (ks + 1 < DIM/32) stage(cur ^ 1, ks + 1);
    s16x8 af[4], bg[2], bu[2];
    #pragma unroll
    for (int m = 0; m < 4; ++m)
      af[m] = *(const s16x8*)((const char*)lA [cur] + aOff + m*1024);
    #pragma unroll
    for (int n = 0; n < 2; ++n){
      bg[n] = *(const s16x8*)((const char*)lBg[cur] + bOff + n*1024);
      bu[n] = *(const s16x8*)((const char*)lBu[cur] + bOff + n*1024);
    }
    #pragma unroll
    for (int m = 0; m < 4; ++m)
      #pragma unroll
      for (int n = 0; n < 2; ++n){
        accg[m][n] = __builtin_amdgcn_mfma_f32_16x16x32_bf16(af[m], bg[n], accg[m][n], 0, 0, 0);
        accu[m][n] = __builtin_amdgcn_mfma_f32_16x16x32_bf16(af[m], bu[n], accu[m][n], 0, 0, 0);
      }
    __syncthreads();
  }
  const int rbase = wr*64 + ((lane >> 4) << 2);
  const int cbase = ti*64 + wc*32 + l15;
  #pragma unroll
  for (int m = 0; m < 4; ++m){
    #pragma unroll
    for (int j = 0; j < 4; ++j){
      const int lr = rbase + m*16 + j;
      const int gi = tm*128 + lr;
      if (gi < cnt){
        __hip_bfloat16* hp = g_h + (size_t)(off + gi)*IDIM + cbase;
        #pragma unroll
        for (int n = 0; n < 2; ++n){
          float gv = accg[m][n][j], uv = accu[m][n][j];
          float hv = gv / (1.f + __expf(-gv)) * uv;   // silu(g)*u
          hp[n*16] = __float2bfloat16(hv);
        }
      }
    }
  }
}

// ---------------- stage B: y[ks] = h @ Wd[K-half ks] (compact, unscaled) ----------------
// 128M x 64N tile, K-split 2 (each block K=1024), 4 waves. LDS 24KB.
__global__ __launch_bounds__(256, 4) void k_mlp2(){
  const int e = blockIdx.z;
  const int flat  = blockIdx.x + 16*blockIdx.y;   // 512 blocks/expert
  const int flat2 = (flat & 7)*64 + (flat >> 3);
  const int tm = flat2 & 15, bdks = flat2 >> 4;   // bdks in [0,32)
  const int bd = bdks & 15, kh = bdks >> 4;       // 16 col-tiles x 2 K-halves
  const int cnt = g_meta[e];
  if (tm*128 >= cnt) return;
  const int off = g_meta[16+e];
  __shared__ __align__(16) __hip_bfloat16 lA[2][128*32];    // 16KB
  __shared__ __align__(16) __hip_bfloat16 lB[2][64*32];     // 8KB
  const int t = threadIdx.x, w = t >> 6, lane = t & 63;
  const int r  = t >> 2, kq = t & 3;
  const int swb = ((kq ^ (r & 3) ^ ((r >> 2) & 3)) << 4);
  const int h0 = off + min(tm*128 + r,      cnt-1);
  const int h1 = off + min(tm*128 + r + 64, cnt-1);
  const size_t khOff = (size_t)kh*1024*2;        // byte offset of K-half
  const char* sA0 = (const char*)(g_h + (size_t)h0*IDIM) + khOff + swb;
  const char* sA1 = (const char*)(g_h + (size_t)h1*IDIM) + khOff + swb;
  const size_t wB = ((size_t)e*DIM + (size_t)bd*64 + r)*IDIM;
  const char* sB0 = (const char*)(g_wdT + wB) + khOff + swb;
  const int dA = w*1024;
  auto stage = [&](int b, int ks){
    const int kb = ks*64;
    load_lds16(sA0+kb, (char*)lA[b] + dA);
    load_lds16(sA1+kb, (char*)lA[b] + dA + 4096);
    load_lds16(sB0+kb, (char*)lB[b] + dA);
  };
  f32x4 acc[4][2] = {};
  const int wr = w >> 1, wc = w & 1;
  const int l15 = lane & 15;
  const int swr = (((lane >> 4) ^ (lane & 3) ^ ((lane >> 2) & 3)) << 4);
  const int aOff = (wr*64 + l15)*64 + swr;
  const int bOff = (wc*32 + l15)*64 + swr;
  stage(0, 0);
  __syncthreads();
  for (int ks = 0; ks < 32; ++ks){               // K-half = 1024 = 32 x BK32
    const int cur = ks & 1;
    if (ks + 1 < 32) stage(cur ^ 1, ks + 1);
    s16x8 af[4], bw[2];
    #pragma unroll
    for (int m = 0; m < 4; ++m)
      af[m] = *(const s16x8*)((const char*)lA[cur] + aOff + m*1024);
    #pragma unroll
    for (int n = 0; n < 2; ++n)
      bw[n] = *(const s16x8*)((const char*)lB[cur] + bOff + n*1024);
    #pragma unroll
    for (int m = 0; m < 4; ++m)
      #pragma unroll
      for (int n = 0; n < 2; ++n)
        acc[m][n] = __builtin_amdgcn_mfma_f32_16x16x32_bf16(af[m], bw[n], acc[m][n], 0, 0, 0);
    __syncthreads();
  }
  const int rbase = wr*64 + ((lane >> 4) << 2);
  const int cb = bd*64 + wc*32 + l15;
  #pragma unroll
  for (int m = 0; m < 4; ++m){
    #pragma unroll
    for (int j = 0; j < 4; ++j){
      const int lr = rbase + m*16 + j;
      const int gi = tm*128 + lr;
      if (gi < cnt){
        float* yp = g_y + ((size_t)kh*(N_TOK*2) + (off + gi))*DIM + cb;
        #pragma unroll
        for (int n = 0; n < 2; ++n)
          yp[n*16] = acc[m][n][j];
      }
    }
  }
}

// ---------------- combine: out[n] = p0*(y0+y1)[s0] + p1*(y0+y1)[s1] ----------------
__global__ void k_combine(float* __restrict__ out){
  const int n = blockIdx.x, t = threadIdx.x;     // 256 threads, one float4 each
  const int s0 = g_slot[n*2], s1 = g_slot[n*2+1];
  const float p0 = g_probs[s0], p1 = g_probs[s1];
  const float4* y0 = (const float4*)g_y;
  const float4* y1 = (const float4*)(g_y + (size_t)(N_TOK*2)*DIM);
  float4 a0 = y0[(size_t)s0*(DIM/4) + t], a1 = y1[(size_t)s0*(DIM/4) + t];
  float4 b0 = y0[(size_t)s1*(DIM/4) + t], b1 = y1[(size_t)s1*(DIM/4) + t];
  float4 o;
  o.x = p0*(a0.x+a1.x) + p1*(b0.x+b1.x);
  o.y = p0*(a0.y+a1.y) + p1*(b0.y+b1.y);
  o.z = p0*(a0.z+a1.z) + p1*(b0.z+b1.z);
  o.w = p0*(a0.w+a1.w) + p1*(b0.w+b1.w);
  ((float4*)(out + (size_t)n*DIM))[t] = o;
}

extern "C" void kernel_launch(void* const* d_in, const int* in_sizes, int n_in,
                              void* d_out, int out_size, void* d_ws, size_t ws_size,
                              hipStream_t stream){
  (void)in_sizes; (void)n_in; (void)d_ws; (void)ws_size; (void)out_size;
  const float* x  = (const float*)d_in[0];
  const float* wr = (const float*)d_in[1];
  const float* wg = (const float*)d_in[2];
  const float* wu = (const float*)d_in[3];
  const float* wd = (const float*)d_in[4];
  float* out = (float*)d_out;

  k_cast_x      <<<2048, 256, 0, stream>>>(x);
  k_router      <<<N_TOK/4, 256, 0, stream>>>(x, wr);
  k_scan_scatter<<<1, 256, 0, stream>>>();
  k_transpose   <<<dim3(512, NEXP, 3), 256, 0, stream>>>(wg, wu, wd);
  k_mlp1        <<<dim3(16, 32, NEXP), 256, 0, stream>>>();
  k_mlp2        <<<dim3(16, 32, NEXP), 256, 0, stream>>>();
  k_combine     <<<N_TOK, 256, 0, stream>>>(out);
}

// Round 10
// 349.786 us; speedup vs baseline: 1.3894x; 1.1846x over previous
//
#include <hip/hip_runtime.h>
#include <hip/hip_bf16.h>
#include <stdint.h>

// MoE SwiGLU, sparse top-2 routing, bf16 MFMA GEMMs, fp32 accumulate.
// N=2048 tokens, D=1024, I=2048, E=8, top_k=2 (hard-coded).
// Round 10: (a) vectorized in-register-transpose weight prep (was 87us at
// 2.3TB/s, issue-bound: VALU 5%, 128B write segments); (b) atomic-free
// router + ballot-based deterministic scatter (removes serialized global
// atomics, suspected hidden ~tens of us).

#define N_TOK 2048
#define DIM   1024
#define IDIM  2048
#define NEXP  8

typedef short s16x8 __attribute__((ext_vector_type(8)));   // 8 bf16 bit-patterns (4 VGPRs)
typedef float f32x4 __attribute__((ext_vector_type(4)));

// Static device scratch. ~153 MB total.
__device__ __align__(256) __hip_bfloat16 g_xb [(size_t)N_TOK*DIM];        // x in bf16
__device__ __align__(256) __hip_bfloat16 g_wgT[(size_t)NEXP*IDIM*DIM];    // w_gate^T  [e][i][d]
__device__ __align__(256) __hip_bfloat16 g_wuT[(size_t)NEXP*IDIM*DIM];    // w_up^T    [e][i][d]
__device__ __align__(256) __hip_bfloat16 g_wdT[(size_t)NEXP*DIM*IDIM];    // w_down^T  [e][d][i]
__device__ __align__(256) __hip_bfloat16 g_h  [(size_t)N_TOK*2*IDIM];     // silu(g)*u, compact rows
__device__ __align__(256) float          g_y  [(size_t)2*N_TOK*2*DIM];    // h @ Wd partials (2 K-halves)
__device__ int   g_topi[N_TOK*2];
__device__ float g_topp[N_TOK*2];
__device__ int   g_rows[N_TOK*2];    // per-expert compact token lists
__device__ int   g_slot[N_TOK*2];    // token -> its 2 compact slots
__device__ float g_probs[N_TOK*2];   // per-slot combine prob
__device__ int   g_meta[32];         // [0:8) counts, [16:24) offsets

__device__ __forceinline__ void load_lds16(const void* g, void* l){
  // 16B-per-lane direct global->LDS (dest = wave-uniform base + lane*16)
  __builtin_amdgcn_global_load_lds(
      (const __attribute__((address_space(1))) unsigned int*)g,
      (__attribute__((address_space(3))) unsigned int*)l, 16, 0, 0);
}

// ---------------- prep: x -> bf16 ----------------
__global__ void k_cast_x(const float* __restrict__ x){
  int i = blockIdx.x*256 + threadIdx.x;          // 524288 float4s total
  float4 v = ((const float4*)x)[i];
  union { ushort4 u; __hip_bfloat16 b[4]; } o;
  o.b[0] = __float2bfloat16(v.x); o.b[1] = __float2bfloat16(v.y);
  o.b[2] = __float2bfloat16(v.z); o.b[3] = __float2bfloat16(v.w);
  ((ushort4*)g_xb)[i] = o.u;
}

// ---------------- prep: transpose + cast the 3 weight tensors ----------------
// 128 src-rows x 64 src-cols per block. Read 4x4 fp32 blocks, in-register
// transpose + cast to bf16, LDS [c][r] bf16 (stride 264B, vector ops both
// phases), write 256B-contiguous dst segments.
__global__ __launch_bounds__(256) void k_transpose(const float* __restrict__ wg,
                                                   const float* __restrict__ wu,
                                                   const float* __restrict__ wd){
  __shared__ __align__(16) __hip_bfloat16 tile[64][132];   // [c][r], 16.9KB
  const int which = blockIdx.z;
  const int e     = blockIdx.y;
  const int R = (which == 2) ? IDIM : DIM;     // src rows
  const int C = (which == 2) ? DIM  : IDIM;    // src cols
  const float* src = ((which == 0) ? wg : (which == 1) ? wu : wd) + (size_t)e*DIM*IDIM;
  __hip_bfloat16* dst = ((which == 0) ? g_wgT : (which == 1) ? g_wuT : g_wdT) + (size_t)e*DIM*IDIM;
  const int ntr = R >> 7;
  const int tr = blockIdx.x % ntr, tc = blockIdx.x / ntr;
  const int r0 = tr*128, c0 = tc*64;
  const int t = threadIdx.x;
  const int c4 = (t & 15)*4;
  #pragma unroll
  for (int it = 0; it < 2; ++it){
    const int r4 = ((t >> 4) + it*16)*4;       // 0..124
    const float* sp = src + (size_t)(r0 + r4)*C + c0 + c4;
    float4 v0 = *(const float4*)(sp);
    float4 v1 = *(const float4*)(sp + C);
    float4 v2 = *(const float4*)(sp + 2*C);
    float4 v3 = *(const float4*)(sp + 3*C);
    union { __hip_bfloat16 b[4]; ushort4 u; } q;
    q.b[0]=__float2bfloat16(v0.x); q.b[1]=__float2bfloat16(v1.x);
    q.b[2]=__float2bfloat16(v2.x); q.b[3]=__float2bfloat16(v3.x);
    *(ushort4*)&tile[c4+0][r4] = q.u;
    q.b[0]=__float2bfloat16(v0.y); q.b[1]=__float2bfloat16(v1.y);
    q.b[2]=__float2bfloat16(v2.y); q.b[3]=__float2bfloat16(v3.y);
    *(ushort4*)&tile[c4+1][r4] = q.u;
    q.b[0]=__float2bfloat16(v0.z); q.b[1]=__float2bfloat16(v1.z);
    q.b[2]=__float2bfloat16(v2.z); q.b[3]=__float2bfloat16(v3.z);
    *(ushort4*)&tile[c4+2][r4] = q.u;
    q.b[0]=__float2bfloat16(v0.w); q.b[1]=__float2bfloat16(v1.w);
    q.b[2]=__float2bfloat16(v2.w); q.b[3]=__float2bfloat16(v3.w);
    *(ushort4*)&tile[c4+3][r4] = q.u;
  }
  __syncthreads();
  #pragma unroll
  for (int it = 0; it < 4; ++it){
    const int s = t + it*256;
    const int ci = s >> 4, r8 = (s & 15)*8;
    ushort4 a = *(const ushort4*)&tile[ci][r8];
    ushort4 b = *(const ushort4*)&tile[ci][r8+4];
    union { ushort4 u[2]; uint4 v; } q; q.u[0] = a; q.u[1] = b;
    *(uint4*)((unsigned short*)dst + (size_t)(c0+ci)*R + r0 + r8) = q.v;
  }
}

// ---------------- router: logits, top-2, softmax (no atomics) ----------------
__global__ void k_router(const float* __restrict__ x, const float* __restrict__ wr){
  const int w = threadIdx.x >> 6, lane = threadIdx.x & 63;
  const int n = blockIdx.x*4 + w;                // one wave per token
  float acc[8] = {0,0,0,0,0,0,0,0};
  const float* xrow = x + (size_t)n*DIM;
  #pragma unroll
  for (int i = 0; i < 16; ++i){
    int d = lane + i*64;
    float xv = xrow[d];
    const float4* wp = (const float4*)(wr + (size_t)d*8);
    float4 w0 = wp[0], w1 = wp[1];
    acc[0] += xv*w0.x; acc[1] += xv*w0.y; acc[2] += xv*w0.z; acc[3] += xv*w0.w;
    acc[4] += xv*w1.x; acc[5] += xv*w1.y; acc[6] += xv*w1.z; acc[7] += xv*w1.w;
  }
  #pragma unroll
  for (int e = 0; e < 8; ++e)
    #pragma unroll
    for (int off = 32; off; off >>= 1) acc[e] += __shfl_xor(acc[e], off);
  if (lane == 0){
    int i0 = -1, i1 = -1; float m0 = -1e30f, m1 = -1e30f;
    #pragma unroll
    for (int e = 0; e < 8; ++e){
      float v = acc[e];
      if (v > m0){ m1 = m0; i1 = i0; m0 = v; i0 = e; }
      else if (v > m1){ m1 = v; i1 = e; }
    }
    float ex = expf(m1 - m0);
    float p0 = 1.f/(1.f+ex), p1 = ex/(1.f+ex);
    g_topi[n*2]   = i0; g_topi[n*2+1] = i1;
    g_topp[n*2]   = p0; g_topp[n*2+1] = p1;
  }
}

// ---------------- scatter: ballot-based stable compaction, 1 block/expert ----------------
__global__ void k_scatter(){
  const int e = blockIdx.x;                      // 8 blocks
  __shared__ int wsum[4];
  const int t = threadIdx.x, w = t >> 6, lane = t & 63;
  // pass 1: counts (c_lt -> offset, c_eq -> count), packed 16/16
  int clt = 0, ceq = 0;
  for (int s = t; s < N_TOK*2; s += 256){
    int v = g_topi[s];
    clt += (v < e); ceq += (v == e);
  }
  int p = clt | (ceq << 16);
  #pragma unroll
  for (int o = 32; o; o >>= 1) p += __shfl_xor(p, o);
  if (lane == 0) wsum[w] = p;
  __syncthreads();
  const int tot = wsum[0] + wsum[1] + wsum[2] + wsum[3];
  const int off = tot & 0xFFFF, cnt = tot >> 16;
  if (t == 0){ g_meta[e] = cnt; g_meta[16+e] = off; }
  __syncthreads();
  // pass 2: stable compaction in slot order (deterministic)
  int run = off;
  for (int s0 = 0; s0 < N_TOK*2; s0 += 256){
    const int s = s0 + t;                        // 4096 = 16*256 exact
    const bool m = (g_topi[s] == e);
    unsigned long long mask = __ballot(m);
    int pre  = __popcll(mask & ((1ULL << lane) - 1ULL));
    int wcnt = __popcll(mask);
    if (lane == 0) wsum[w] = wcnt;
    __syncthreads();
    int wbase = 0;
    #pragma unroll
    for (int i = 0; i < 4; ++i) if (i < w) wbase += wsum[i];
    const int itot = wsum[0] + wsum[1] + wsum[2] + wsum[3];
    if (m){
      int slot = run + wbase + pre;
      g_rows [slot] = s >> 1;
      g_probs[slot] = g_topp[s];
      g_slot [s]    = slot;
    }
    run += itot;
    __syncthreads();
  }
}

// ---------------- stage A: h = silu(x@Wg) * (x@Wu), per expert ----------------
// 128M x 64N tile, BK=32, 4 waves (each 64x32, acc 4x2x2). LDS 32KB.
__global__ __launch_bounds__(256, 4) void k_mlp1(){
  const int e = blockIdx.z;
  // XCD swizzle of the 512-block (tm,ti) plane (512 % 8 == 0 -> bijective)
  const int flat  = blockIdx.x + 16*blockIdx.y;
  const int flat2 = (flat & 7)*64 + (flat >> 3);
  const int tm = flat2 & 15, ti = flat2 >> 4;    // ti in [0,32)
  const int cnt = g_meta[e];
  if (tm*128 >= cnt) return;
  const int off = g_meta[16+e];
  __shared__ __align__(16) __hip_bfloat16 lA [2][128*32];   // 16KB
  __shared__ __align__(16) __hip_bfloat16 lBg[2][64*32];    // 8KB
  __shared__ __align__(16) __hip_bfloat16 lBu[2][64*32];    // 8KB
  const int t = threadIdx.x, w = t >> 6, lane = t & 63;
  // --- staging: thread t owns row r=t>>2 (A also r+64), k-quarter kq=t&3 ---
  const int r  = t >> 2, kq = t & 3;
  const int swb = ((kq ^ (r & 3) ^ ((r >> 2) & 3)) << 4);   // S(r) invariant under r+=64
  const int tok0 = g_rows[off + min(tm*128 + r,      cnt-1)];
  const int tok1 = g_rows[off + min(tm*128 + r + 64, cnt-1)];
  const char* sA0 = (const char*)(g_xb + (size_t)tok0*DIM) + swb;
  const char* sA1 = (const char*)(g_xb + (size_t)tok1*DIM) + swb;
  const size_t wB = ((size_t)e*IDIM + (size_t)ti*64)*DIM;
  const char* sG0 = (const char*)(g_wgT + wB + (size_t)r*DIM) + swb;
  const char* sU0 = (const char*)(g_wuT + wB + (size_t)r*DIM) + swb;
  const int dA = w*1024;                         // wave-uniform LDS bases
  auto stage = [&](int b, int ks){
    const int kb = ks*64;
    load_lds16(sA0+kb, (char*)lA [b] + dA);
    load_lds16(sA1+kb, (char*)lA [b] + dA + 4096);
    load_lds16(sG0+kb, (char*)lBg[b] + dA);
    load_lds16(sU0+kb, (char*)lBu[b] + dA);
  };
  f32x4 accg[4][2] = {}, accu[4][2] = {};
  const int wr = w >> 1, wc = w & 1;
  const int l15 = lane & 15;
  const int swr = (((lane >> 4) ^ (lane & 3) ^ ((lane >> 2) & 3)) << 4);
  const int aOff = (wr*64 + l15)*64 + swr;
  const int bOff = (wc*32 + l15)*64 + swr;
  stage(0, 0);
  __syncthreads();
  for (int ks = 0; ks < DIM/32; ++ks){
    const int cur = ks & 1;
    if (ks + 1 < DIM/32) stage(cur ^ 1, ks + 1);
    s16x8 af[4], bg[2], bu[2];
    #pragma unroll
    for (int m = 0; m < 4; ++m)
      af[m] = *(const s16x8*)((const char*)lA [cur] + aOff + m*1024);
    #pragma unroll
    for (int n = 0; n < 2; ++n){
      bg[n] = *(const s16x8*)((const char*)lBg[cur] + bOff + n*1024);
      bu[n] = *(const s16x8*)((const char*)lBu[cur] + bOff + n*1024);
    }
    #pragma unroll
    for (int m = 0; m < 4; ++m)
      #pragma unroll
      for (int n = 0; n < 2; ++n){
        accg[m][n] = __builtin_amdgcn_mfma_f32_16x16x32_bf16(af[m], bg[n], accg[m][n], 0, 0, 0);
        accu[m][n] = __builtin_amdgcn_mfma_f32_16x16x32_bf16(af[m], bu[n], accu[m][n], 0, 0, 0);
      }
    __syncthreads();
  }
  const int rbase = wr*64 + ((lane >> 4) << 2);
  const int cbase = ti*64 + wc*32 + l15;
  #pragma unroll
  for (int m = 0; m < 4; ++m){
    #pragma unroll
    for (int j = 0; j < 4; ++j){
      const int lr = rbase + m*16 + j;
      const int gi = tm*128 + lr;
      if (gi < cnt){
        __hip_bfloat16* hp = g_h + (size_t)(off + gi)*IDIM + cbase;
        #pragma unroll
        for (int n = 0; n < 2; ++n){
          float gv = accg[m][n][j], uv = accu[m][n][j];
          float hv = gv / (1.f + __expf(-gv)) * uv;   // silu(g)*u
          hp[n*16] = __float2bfloat16(hv);
        }
      }
    }
  }
}

// ---------------- stage B: y[ks] = h @ Wd[K-half ks] (compact, unscaled) ----------------
// 128M x 64N tile, K-split 2 (each block K=1024), 4 waves. LDS 24KB.
__global__ __launch_bounds__(256, 4) void k_mlp2(){
  const int e = blockIdx.z;
  const int flat  = blockIdx.x + 16*blockIdx.y;   // 512 blocks/expert
  const int flat2 = (flat & 7)*64 + (flat >> 3);
  const int tm = flat2 & 15, bdks = flat2 >> 4;   // bdks in [0,32)
  const int bd = bdks & 15, kh = bdks >> 4;       // 16 col-tiles x 2 K-halves
  const int cnt = g_meta[e];
  if (tm*128 >= cnt) return;
  const int off = g_meta[16+e];
  __shared__ __align__(16) __hip_bfloat16 lA[2][128*32];    // 16KB
  __shared__ __align__(16) __hip_bfloat16 lB[2][64*32];     // 8KB
  const int t = threadIdx.x, w = t >> 6, lane = t & 63;
  const int r  = t >> 2, kq = t & 3;
  const int swb = ((kq ^ (r & 3) ^ ((r >> 2) & 3)) << 4);
  const int h0 = off + min(tm*128 + r,      cnt-1);
  const int h1 = off + min(tm*128 + r + 64, cnt-1);
  const size_t khOff = (size_t)kh*1024*2;        // byte offset of K-half
  const char* sA0 = (const char*)(g_h + (size_t)h0*IDIM) + khOff + swb;
  const char* sA1 = (const char*)(g_h + (size_t)h1*IDIM) + khOff + swb;
  const size_t wB = ((size_t)e*DIM + (size_t)bd*64 + r)*IDIM;
  const char* sB0 = (const char*)(g_wdT + wB) + khOff + swb;
  const int dA = w*1024;
  auto stage = [&](int b, int ks){
    const int kb = ks*64;
    load_lds16(sA0+kb, (char*)lA[b] + dA);
    load_lds16(sA1+kb, (char*)lA[b] + dA + 4096);
    load_lds16(sB0+kb, (char*)lB[b] + dA);
  };
  f32x4 acc[4][2] = {};
  const int wr = w >> 1, wc = w & 1;
  const int l15 = lane & 15;
  const int swr = (((lane >> 4) ^ (lane & 3) ^ ((lane >> 2) & 3)) << 4);
  const int aOff = (wr*64 + l15)*64 + swr;
  const int bOff = (wc*32 + l15)*64 + swr;
  stage(0, 0);
  __syncthreads();
  for (int ks = 0; ks < 32; ++ks){               // K-half = 1024 = 32 x BK32
    const int cur = ks & 1;
    if (ks + 1 < 32) stage(cur ^ 1, ks + 1);
    s16x8 af[4], bw[2];
    #pragma unroll
    for (int m = 0; m < 4; ++m)
      af[m] = *(const s16x8*)((const char*)lA[cur] + aOff + m*1024);
    #pragma unroll
    for (int n = 0; n < 2; ++n)
      bw[n] = *(const s16x8*)((const char*)lB[cur] + bOff + n*1024);
    #pragma unroll
    for (int m = 0; m < 4; ++m)
      #pragma unroll
      for (int n = 0; n < 2; ++n)
        acc[m][n] = __builtin_amdgcn_mfma_f32_16x16x32_bf16(af[m], bw[n], acc[m][n], 0, 0, 0);
    __syncthreads();
  }
  const int rbase = wr*64 + ((lane >> 4) << 2);
  const int cb = bd*64 + wc*32 + l15;
  #pragma unroll
  for (int m = 0; m < 4; ++m){
    #pragma unroll
    for (int j = 0; j < 4; ++j){
      const int lr = rbase + m*16 + j;
      const int gi = tm*128 + lr;
      if (gi < cnt){
        float* yp = g_y + ((size_t)kh*(N_TOK*2) + (off + gi))*DIM + cb;
        #pragma unroll
        for (int n = 0; n < 2; ++n)
          yp[n*16] = acc[m][n][j];
      }
    }
  }
}

// ---------------- combine: out[n] = p0*(y0+y1)[s0] + p1*(y0+y1)[s1] ----------------
__global__ void k_combine(float* __restrict__ out){
  const int n = blockIdx.x, t = threadIdx.x;     // 256 threads, one float4 each
  const int s0 = g_slot[n*2], s1 = g_slot[n*2+1];
  const float p0 = g_probs[s0], p1 = g_probs[s1];
  const float4* y0 = (const float4*)g_y;
  const float4* y1 = (const float4*)(g_y + (size_t)(N_TOK*2)*DIM);
  float4 a0 = y0[(size_t)s0*(DIM/4) + t], a1 = y1[(size_t)s0*(DIM/4) + t];
  float4 b0 = y0[(size_t)s1*(DIM/4) + t], b1 = y1[(size_t)s1*(DIM/4) + t];
  float4 o;
  o.x = p0*(a0.x+a1.x) + p1*(b0.x+b1.x);
  o.y = p0*(a0.y+a1.y) + p1*(b0.y+b1.y);
  o.z = p0*(a0.z+a1.z) + p1*(b0.z+b1.z);
  o.w = p0*(a0.w+a1.w) + p1*(b0.w+b1.w);
  ((float4*)(out + (size_t)n*DIM))[t] = o;
}

extern "C" void kernel_launch(void* const* d_in, const int* in_sizes, int n_in,
                              void* d_out, int out_size, void* d_ws, size_t ws_size,
                              hipStream_t stream){
  (void)in_sizes; (void)n_in; (void)d_ws; (void)ws_size; (void)out_size;
  const float* x  = (const float*)d_in[0];
  const float* wr = (const float*)d_in[1];
  const float* wg = (const float*)d_in[2];
  const float* wu = (const float*)d_in[3];
  const float* wd = (const float*)d_in[4];
  float* out = (float*)d_out;

  k_cast_x   <<<2048, 256, 0, stream>>>(x);
  k_router   <<<N_TOK/4, 256, 0, stream>>>(x, wr);
  k_scatter  <<<NEXP, 256, 0, stream>>>();
  k_transpose<<<dim3(256, NEXP, 3), 256, 0, stream>>>(wg, wu, wd);
  k_mlp1     <<<dim3(16, 32, NEXP), 256, 0, stream>>>();
  k_mlp2     <<<dim3(16, 32, NEXP), 256, 0, stream>>>();
  k_combine  <<<N_TOK, 256, 0, stream>>>(out);
}